// Round 10
// baseline (256.952 us; speedup 1.0000x reference)
//
#include <hip/hip_runtime.h>

#define N_NODES 8192
#define N_EDGES 262144
#define IN_CH 128
#define MP_CH 512
#define HID 256
#define KCL 10
#define EPS_C 0.001f
#define DELTA_C 0.311f
#define TV_COEFF_C 0.785f
#define BAL_COEFF_C 0.514f
#define RANK1 7373  // N - (N/K+1) + 1 : want smallest v with count(<=v) >= RANK1
#define DBINS 80    // degree histogram bins for load-balance sort

// LESSON (R1-R3, quantified R9): same-line device atomics serialize at ~50ns/op across the
// 8 non-coherent XCD L2s (2048 atomics = 100us, matched exactly). Budget: <= ~256 per launch.
// LESSON (R6-R8): gtv_node (~32us/pass) is at its scattered-gather ceiling; the 2-waves/node
// shfl structure with parallel 1KB gathers is the proven optimum (3 alternatives null/worse).
// R10: n_edges via dedup-count at 256 block-level atomics (window logic verified in R2/R3;
// their 100us was PURELY the 2048-atomic chain). Bitmap + popcfin deleted.

typedef __bf16 bf16x8 __attribute__((ext_vector_type(8)));
typedef float f32x4 __attribute__((ext_vector_type(4)));
typedef unsigned short ushort8 __attribute__((ext_vector_type(8)));

__device__ __forceinline__ float bf2f(unsigned short h) {
  union { unsigned int u; float f; } c; c.u = ((unsigned int)h) << 16; return c.f;
}
__device__ __forceinline__ unsigned short f2bf(float f) {
  union { float f; unsigned int u; } c; c.f = f;
  unsigned int r = c.u + 0x7fffu + ((c.u >> 16) & 1u);
  return (unsigned short)(r >> 16);
}

// ---------------- fused prep: bf16 converts + weight transposes + dst histogram -------------
__global__ void prep_kernel(const float* __restrict__ x, const float* __restrict__ W1,
                            const float* __restrict__ W2, const float* __restrict__ Wm1,
                            unsigned short* __restrict__ xb, unsigned short* __restrict__ W1bt,
                            unsigned short* __restrict__ W2bt, unsigned short* __restrict__ Wm1bt,
                            const int* __restrict__ dst, int* __restrict__ cnt) {
  int i = blockIdx.x * 256 + threadIdx.x;
  if (i < 1048576) { xb[i] = f2bf(x[i]); return; }
  i -= 1048576;
  if (i < 65536) { int n = i >> 7, k = i & 127; W1bt[i] = f2bf(W1[k * MP_CH + n]); return; }
  i -= 65536;
  if (i < 262144) { int n = i >> 9, k = i & 511; W2bt[i] = f2bf(W2[k * MP_CH + n]); return; }
  i -= 262144;
  if (i < 131072) { int n = i >> 9, k = i & 511; Wm1bt[i] = f2bf(Wm1[k * HID + n]); return; }
  i -= 131072;
  if (i < N_EDGES) atomicAdd(&cnt[dst[i]], 1);
}

// ---------------- merged: layer-1 GEMM (blocks 0..255) + 256-thread scan (block 256) --------
__global__ __launch_bounds__(256) void gemm1_scan(
    const unsigned short* __restrict__ A, const unsigned short* __restrict__ BT,
    unsigned short* __restrict__ Cb, const int* __restrict__ cnt, int* __restrict__ offs,
    int* __restrict__ cursor, int* __restrict__ nodeorder) {
  if (blockIdx.x < 256) {
    // ---- layer-1 GEMM tile: N=512, K=128; tn = (bid&3)*128, tm = (bid>>2)*128 ----
    __shared__ unsigned short lsm[2 * 128 * 32];
    unsigned short* lA = lsm;
    unsigned short* lB = lsm + 128 * 32;
    const int N = MP_CH, K = IN_CH;
    int lane = threadIdx.x & 63;
    int wv = threadIdx.x >> 6;
    int tm = (blockIdx.x >> 2) * 128, tn = (blockIdx.x & 3) * 128;
    int wm = (wv >> 1) * 64, wn = (wv & 1) * 64;
    int rA = lane & 15, quad = lane >> 4;
    f32x4 acc[4][4];
#pragma unroll
    for (int i = 0; i < 4; ++i)
#pragma unroll
      for (int j = 0; j < 4; ++j) acc[i][j] = (f32x4){0.f, 0.f, 0.f, 0.f};
    int arow = wv * 32 + (lane >> 2);
    int acol = (lane & 3) * 8;
    for (int k0 = 0; k0 < K; k0 += 32) {
#pragma unroll
      for (int c = 0; c < 2; ++c) {
        const unsigned short* ga = A + (size_t)(tm + arow + c * 16) * K + k0 + acol;
        __builtin_amdgcn_global_load_lds(
            (const __attribute__((address_space(1))) unsigned int*)ga,
            (__attribute__((address_space(3))) unsigned int*)(lA + (wv * 32 + c * 16) * 32),
            16, 0, 0);
        const unsigned short* gb = BT + (size_t)(tn + arow + c * 16) * K + k0 + acol;
        __builtin_amdgcn_global_load_lds(
            (const __attribute__((address_space(1))) unsigned int*)gb,
            (__attribute__((address_space(3))) unsigned int*)(lB + (wv * 32 + c * 16) * 32),
            16, 0, 0);
      }
      __syncthreads();
      bf16x8 af[4], bfr[4];
#pragma unroll
      for (int i = 0; i < 4; ++i)
        af[i] = *(const bf16x8*)(lA + (wm + i * 16 + rA) * 32 + quad * 8);
#pragma unroll
      for (int j = 0; j < 4; ++j)
        bfr[j] = *(const bf16x8*)(lB + (wn + j * 16 + rA) * 32 + quad * 8);
#pragma unroll
      for (int i = 0; i < 4; ++i)
#pragma unroll
        for (int j = 0; j < 4; ++j)
          acc[i][j] = __builtin_amdgcn_mfma_f32_16x16x32_bf16(af[i], bfr[j], acc[i][j], 0, 0, 0);
      __syncthreads();
    }
    float* fbuf = (float*)lsm;
    int band = threadIdx.x >> 7;
    int rrow = (threadIdx.x >> 3) & 15;
    int cg = threadIdx.x & 7;
#pragma unroll
    for (int i = 0; i < 4; ++i) {
#pragma unroll
      for (int j = 0; j < 4; ++j)
#pragma unroll
        for (int r = 0; r < 4; ++r)
          fbuf[(wv >> 1) * (16 * 128) + (quad * 4 + r) * 128 + (wn + j * 16 + rA)] =
              acc[i][j][r];
      __syncthreads();
      const float* sr = fbuf + band * (16 * 128) + rrow * 128 + cg * 16;
      unsigned short ov[16];
#pragma unroll
      for (int c = 0; c < 16; ++c) ov[c] = f2bf(sr[c]);
      size_t gbase = (size_t)(tm + band * 64 + i * 16 + rrow) * N + tn + cg * 16;
      *(ushort8*)(Cb + gbase) = *(ushort8*)ov;
      *(ushort8*)(Cb + gbase + 8) = *(ushort8*)(ov + 8);
      __syncthreads();
    }
  } else {
    // ---- 256-thread scan: prefix-sum + degree-descending counting sort (R1-verified) ----
    __shared__ int ts[256];
    __shared__ int dh[DBINS];
    int t = threadIdx.x;
    int v[32]; int ssum = 0;
#pragma unroll
    for (int j = 0; j < 32; ++j) { v[j] = cnt[t * 32 + j]; ssum += v[j]; }
    if (t < DBINS) dh[t] = 0;
    ts[t] = ssum; __syncthreads();
    for (int off = 1; off < 256; off <<= 1) {
      int add = (t >= off) ? ts[t - off] : 0;
      __syncthreads();
      ts[t] += add;
      __syncthreads();
    }
    int base = ts[t] - ssum;  // exclusive prefix
#pragma unroll
    for (int j = 0; j < 32; ++j) {
      offs[t * 32 + j] = base; cursor[t * 32 + j] = base; base += v[j];
      int key = v[j] < (DBINS - 1) ? v[j] : (DBINS - 1);
      atomicAdd(&dh[(DBINS - 1) - key], 1);  // descending-degree bins
    }
    if (t == 255) offs[N_NODES] = ts[255];
    __syncthreads();
    if (t == 0) {
      int acc0 = 0;
      for (int b = 0; b < DBINS; ++b) { int c = dh[b]; dh[b] = acc0; acc0 += c; }
    }
    __syncthreads();
#pragma unroll
    for (int j = 0; j < 32; ++j) {
      int key = v[j] < (DBINS - 1) ? v[j] : (DBINS - 1);
      int pos = atomicAdd(&dh[(DBINS - 1) - key], 1);
      nodeorder[pos] = t * 32 + j;
    }
  }
}

// pack (src, weight) sorted by dst
__global__ void fill_kernel(const int* __restrict__ src, const int* __restrict__ dst,
                            const float* __restrict__ ew, int* __restrict__ cursor,
                            int2* __restrict__ esw) {
  for (int e = blockIdx.x * blockDim.x + threadIdx.x; e < N_EDGES; e += gridDim.x * blockDim.x) {
    int p = atomicAdd(&cursor[dst[e]], 1);
    esw[p] = make_int2(src[e], __float_as_int(ew[e]));
  }
}

// ---------------- n_edges: distinct (src,dst) with w!=0, 256 block-level atomics ------------
// Window dedup logic verbatim from R2/R3 (verified passing twice); ONLY the accumulation is
// restructured: 256 blocks x 16 waves x 2 nodes, LDS block-reduce, ONE atomicAdd per block.
__global__ __launch_bounds__(1024) void dupcount_kernel(const int2* __restrict__ esw,
                                                        const int* __restrict__ offs,
                                                        float* __restrict__ scal) {
  __shared__ int lsrc[16][320];
  __shared__ int csh[16];
  int t = threadIdx.x;
  int lane = t & 63, wv = t >> 6;
  int c = 0;
#pragma unroll
  for (int nn = 0; nn < 2; ++nn) {
    int d = (blockIdx.x * 16 + wv) * 2 + nn;
    int n0 = offs[d], n1 = offs[d + 1];
    for (int bse = n0; bse < n1; bse += 64) {
      int e = bse + lane;
      int2 me = (e < n1) ? esw[e] : make_int2(-1, 0);
      bool act = (e < n1) && (me.y != 0);
      bool dup = false;
      // intra-window: compare against all earlier lanes via rotation
      unsigned long long am = __ballot(act);
      for (int ofs = 1; ofs < 64; ++ofs) {
        int ol = lane - ofs;
        int osrc = __shfl(me.x, (lane + 64 - ofs) & 63, 64);
        if (act && ol >= 0 && ((am >> ol) & 1ull) && osrc == me.x) dup = true;
      }
      // cross-window: LDS-staged earlier entries of THIS node (staged <= current prefix)
      int idx0 = bse - n0;
      int staged = idx0 < 320 ? idx0 : 320;
      for (int j = 0; j < staged; ++j) {
        if (act && lsrc[wv][j] == me.x) dup = true;
      }
      // unstaged fallback (deg > 384; never for this input, kept for correctness)
      for (int j = n0 + 320; j < bse; ++j) {
        int2 ej = esw[j];
        if (act && ej.y != 0 && ej.x == me.x) dup = true;
      }
      unsigned long long b = __ballot(act && !dup);
      if (lane == 0) c += __popcll(b);
      if (idx0 + lane < 320) lsrc[wv][idx0 + lane] = act ? me.x : -1;
    }
  }
  if (lane == 0) csh[wv] = c;
  __syncthreads();
  if (t == 0) {
    int tot = 0;
#pragma unroll
    for (int i = 0; i < 16; ++i) tot += csh[i];
    if (tot) atomicAdd((int*)(scal + 2), tot);  // 256 same-line atomics: within budget
  }
}

// ---------------- MFMA GEMM: Cb[M,N] bf16 = A[M,K] @ BT[N,K]^T  (layer 2) -------------------
__global__ __launch_bounds__(256) void gemm_bt(
    const unsigned short* __restrict__ A, const unsigned short* __restrict__ BT,
    unsigned short* __restrict__ Cb, int N, int K) {
  __shared__ unsigned short lsm[2 * 128 * 32];  // lA | lB ; reused as f32 buf in epilogue
  unsigned short* lA = lsm;
  unsigned short* lB = lsm + 128 * 32;
  int lane = threadIdx.x & 63;
  int wv = threadIdx.x >> 6;
  int tm = blockIdx.y * 128, tn = blockIdx.x * 128;
  int wm = (wv >> 1) * 64, wn = (wv & 1) * 64;
  int rA = lane & 15, quad = lane >> 4;
  f32x4 acc[4][4];
#pragma unroll
  for (int i = 0; i < 4; ++i)
#pragma unroll
    for (int j = 0; j < 4; ++j) acc[i][j] = (f32x4){0.f, 0.f, 0.f, 0.f};

  int arow = wv * 32 + (lane >> 2);
  int acol = (lane & 3) * 8;

  for (int k0 = 0; k0 < K; k0 += 32) {
#pragma unroll
    for (int c = 0; c < 2; ++c) {
      const unsigned short* ga = A + (size_t)(tm + arow + c * 16) * K + k0 + acol;
      __builtin_amdgcn_global_load_lds(
          (const __attribute__((address_space(1))) unsigned int*)ga,
          (__attribute__((address_space(3))) unsigned int*)(lA + (wv * 32 + c * 16) * 32),
          16, 0, 0);
      const unsigned short* gb = BT + (size_t)(tn + arow + c * 16) * K + k0 + acol;
      __builtin_amdgcn_global_load_lds(
          (const __attribute__((address_space(1))) unsigned int*)gb,
          (__attribute__((address_space(3))) unsigned int*)(lB + (wv * 32 + c * 16) * 32),
          16, 0, 0);
    }
    __syncthreads();
    bf16x8 af[4], bfr[4];
#pragma unroll
    for (int i = 0; i < 4; ++i)
      af[i] = *(const bf16x8*)(lA + (wm + i * 16 + rA) * 32 + quad * 8);
#pragma unroll
    for (int j = 0; j < 4; ++j)
      bfr[j] = *(const bf16x8*)(lB + (wn + j * 16 + rA) * 32 + quad * 8);
#pragma unroll
    for (int i = 0; i < 4; ++i)
#pragma unroll
      for (int j = 0; j < 4; ++j)
        acc[i][j] = __builtin_amdgcn_mfma_f32_16x16x32_bf16(af[i], bfr[j], acc[i][j], 0, 0, 0);
    __syncthreads();
  }

  // LDS re-tile epilogue: coalesced 16B bf16 stores
  float* fbuf = (float*)lsm;
  int band = threadIdx.x >> 7;
  int rrow = (threadIdx.x >> 3) & 15;
  int cg = threadIdx.x & 7;
#pragma unroll
  for (int i = 0; i < 4; ++i) {
#pragma unroll
    for (int j = 0; j < 4; ++j)
#pragma unroll
      for (int r = 0; r < 4; ++r)
        fbuf[(wv >> 1) * (16 * 128) + (quad * 4 + r) * 128 + (wn + j * 16 + rA)] =
            acc[i][j][r];
    __syncthreads();
    const float* sr = fbuf + band * (16 * 128) + rrow * 128 + cg * 16;
    unsigned short ov[16];
#pragma unroll
    for (int c = 0; c < 16; ++c) ov[c] = f2bf(sr[c]);
    size_t gbase = (size_t)(tm + band * 64 + i * 16 + rrow) * N + tn + cg * 16;
    *(ushort8*)(Cb + gbase) = *(ushort8*)ov;
    *(ushort8*)(Cb + gbase + 8) = *(ushort8*)(ov + 8);
    __syncthreads();
  }
}

// ---------------- fused GTV node pass: TWO waves per node (half edge list each) -------------
// R4-proven structure (~32us/pass): parallel 1KB gathers, shfl-butterfly reduce.
__global__ __launch_bounds__(256, 8) void gtv_node(
    const unsigned short* __restrict__ hb, const float* __restrict__ bias,
    const int2* __restrict__ esw, const int* __restrict__ offs,
    const int* __restrict__ nodeorder, unsigned short* __restrict__ outb) {
  __shared__ float sacc[2][MP_CH];
  int lane = threadIdx.x & 63;
  int wv = threadIdx.x >> 6;
  int pair = wv >> 1;          // 0,1 : node slot within block
  int half = wv & 1;           // 0,1 : which half of the edge list
  int d = __builtin_amdgcn_readfirstlane(nodeorder[blockIdx.x * 2 + pair]);
  ushort8 hdv = ((const ushort8*)(hb + (size_t)d * MP_CH))[lane];
  float hd[8], acc[8];
#pragma unroll
  for (int j = 0; j < 8; ++j) { hd[j] = bf2f(hdv[j]); acc[j] = 0.f; }
  int n0 = offs[d], n1 = offs[d + 1];
  int mid = n0 + ((n1 - n0 + 1) >> 1);
  int e0 = half ? mid : n0;
  int e1 = half ? n1 : mid;
  int i = e0;
  for (; i + 1 < e1; i += 2) {
    int2 ma = esw[i], mb = esw[i + 1];
    float wa = __int_as_float(ma.y), wb = __int_as_float(mb.y);
    ushort8 va = ((const ushort8*)(hb + (size_t)ma.x * MP_CH))[lane];
    ushort8 vb = ((const ushort8*)(hb + (size_t)mb.x * MP_CH))[lane];
    float pa = 0.f, pb = 0.f;
#pragma unroll
    for (int j = 0; j < 8; ++j) {
      pa += fabsf(hd[j] - bf2f(va[j]));
      pb += fabsf(hd[j] - bf2f(vb[j]));
    }
#pragma unroll
    for (int m = 1; m < 64; m <<= 1) { pa += __shfl_xor(pa, m, 64); pb += __shfl_xor(pb, m, 64); }
    float ga = wa * __builtin_amdgcn_rcpf(fmaxf(pa, EPS_C));
    float gb = wb * __builtin_amdgcn_rcpf(fmaxf(pb, EPS_C));
#pragma unroll
    for (int j = 0; j < 8; ++j)
      acc[j] += ga * (hd[j] - bf2f(va[j])) + gb * (hd[j] - bf2f(vb[j]));
  }
  if (i < e1) {
    int2 m0 = esw[i];
    float w = __int_as_float(m0.y);
    ushort8 sv = ((const ushort8*)(hb + (size_t)m0.x * MP_CH))[lane];
    float part = 0.f;
#pragma unroll
    for (int j = 0; j < 8; ++j) part += fabsf(hd[j] - bf2f(sv[j]));
#pragma unroll
    for (int m = 1; m < 64; m <<= 1) part += __shfl_xor(part, m, 64);
    float g = w * __builtin_amdgcn_rcpf(fmaxf(part, EPS_C));
#pragma unroll
    for (int j = 0; j < 8; ++j) acc[j] += g * (hd[j] - bf2f(sv[j]));
  }
  // combine halves: half1 publishes, half0 merges + does the epilogue
  if (half) {
#pragma unroll
    for (int j = 0; j < 8; ++j) sacc[pair][lane * 8 + j] = acc[j];
  }
  __syncthreads();
  if (!half) {
    const f32x4* br = (const f32x4*)(bias + lane * 8);
    f32x4 b0 = br[0], b1 = br[1];
    unsigned short ov[8];
#pragma unroll
    for (int j = 0; j < 8; ++j) {
      float tot = acc[j] + sacc[pair][lane * 8 + j];
      float bv = (j < 4) ? b0[j] : b1[j - 4];
      float o = hd[j] - DELTA_C * tot + bv;
      o = (o > 0.f) ? o : (expf(o) - 1.f);
      ov[j] = f2bf(o);
    }
    *((ushort8*)(outb + (size_t)d * MP_CH) + lane) = *(ushort8*)ov;
  }
}

// ---------------- fused MLP head: relu(outb@Wm1+b) in MFMA, then @Wm2+b2, softmax -----------
__global__ __launch_bounds__(256) void head_fused(
    const unsigned short* __restrict__ A,   // outb [8192][512] bf16
    const unsigned short* __restrict__ BT,  // Wm1bt [256][512] bf16
    const float* __restrict__ bm1v, const float* __restrict__ Wm2v,
    const float* __restrict__ bm2v, float* __restrict__ out, float* __restrict__ s) {
  __shared__ unsigned short lA[32 * 32];    // 2 KB
  __shared__ unsigned short lB[256 * 32];   // 16 KB
  __shared__ float hbuf[256 * 41];          // 42 KB, col-major padded
  __shared__ float lW2[HID * KCL];          // 10 KB
  __shared__ float lb1[HID];
  __shared__ float lb2[KCL];
  int t = threadIdx.x;
  int lane = t & 63, wv = t >> 6;
  int rA = lane & 15, quad = lane >> 4;
  int m0 = blockIdx.x * 32;

  for (int i2 = t; i2 < HID * KCL; i2 += 256) lW2[i2] = Wm2v[i2];
  lb1[t < HID ? t : 0] = bm1v[t < HID ? t : 0];
  if (t < KCL) lb2[t] = bm2v[t];

  f32x4 acc[2][4];
#pragma unroll
  for (int i = 0; i < 2; ++i)
#pragma unroll
    for (int j = 0; j < 4; ++j) acc[i][j] = (f32x4){0.f, 0.f, 0.f, 0.f};

  for (int k0 = 0; k0 < MP_CH; k0 += 32) {
    if (wv < 2) {
      int row = wv * 16 + (lane >> 2);
      const unsigned short* ga = A + (size_t)(m0 + row) * MP_CH + k0 + (lane & 3) * 8;
      __builtin_amdgcn_global_load_lds(
          (const __attribute__((address_space(1))) unsigned int*)ga,
          (__attribute__((address_space(3))) unsigned int*)(lA + (wv * 16) * 32), 16, 0, 0);
    }
#pragma unroll
    for (int q = 0; q < 4; ++q) {
      int idx = wv * 4 + q;
      int row = idx * 16 + (lane >> 2);
      const unsigned short* gb = BT + (size_t)row * MP_CH + k0 + (lane & 3) * 8;
      __builtin_amdgcn_global_load_lds(
          (const __attribute__((address_space(1))) unsigned int*)gb,
          (__attribute__((address_space(3))) unsigned int*)(lB + (idx * 16) * 32), 16, 0, 0);
    }
    __syncthreads();
    bf16x8 af[2], bfr[4];
#pragma unroll
    for (int i = 0; i < 2; ++i)
      af[i] = *(const bf16x8*)(lA + (i * 16 + rA) * 32 + quad * 8);
#pragma unroll
    for (int j = 0; j < 4; ++j)
      bfr[j] = *(const bf16x8*)(lB + (wv * 64 + j * 16 + rA) * 32 + quad * 8);
#pragma unroll
    for (int i = 0; i < 2; ++i)
#pragma unroll
      for (int j = 0; j < 4; ++j)
        acc[i][j] = __builtin_amdgcn_mfma_f32_16x16x32_bf16(af[i], bfr[j], acc[i][j], 0, 0, 0);
    __syncthreads();
  }

  // epilogue 1: h = relu(acc + bm1) -> LDS col-major [col][row], stride 41
#pragma unroll
  for (int i = 0; i < 2; ++i)
#pragma unroll
    for (int j = 0; j < 4; ++j)
#pragma unroll
      for (int r = 0; r < 4; ++r) {
        int row = i * 16 + quad * 4 + r;
        int col = wv * 64 + j * 16 + rA;
        hbuf[col * 41 + row] = fmaxf(acc[i][j][r] + lb1[col], 0.f);
      }
  __syncthreads();

  // epilogue 2: s_logits[row] = h[row] @ Wm2 + bm2 ; softmax -> s
  int row = t >> 3, g = t & 7;
  float p[KCL];
#pragma unroll
  for (int n = 0; n < KCL; ++n) p[n] = 0.f;
#pragma unroll
  for (int k = 0; k < 32; ++k) {
    int col = k * 8 + g;
    float hv = hbuf[col * 41 + row];
    const float* wr = lW2 + col * KCL;
#pragma unroll
    for (int n = 0; n < KCL; ++n) p[n] += hv * wr[n];
  }
#pragma unroll
  for (int n = 0; n < KCL; ++n) {
    p[n] += __shfl_xor(p[n], 1, 64);
    p[n] += __shfl_xor(p[n], 2, 64);
    p[n] += __shfl_xor(p[n], 4, 64);
  }
  if (g == 0) {
    float vv[KCL]; float mx = -1e30f;
    size_t gr = (size_t)(m0 + row);
#pragma unroll
    for (int n = 0; n < KCL; ++n) {
      vv[n] = p[n] + lb2[n];
      out[gr * KCL + n] = vv[n];
      mx = fmaxf(mx, vv[n]);
    }
    float sum = 0.f;
#pragma unroll
    for (int n = 0; n < KCL; ++n) { vv[n] = expf(vv[n] - mx); sum += vv[n]; }
    float inv = 1.f / sum;
#pragma unroll
    for (int n = 0; n < KCL; ++n) s[gr * KCL + n] = vv[n] * inv;
  }
}

// ---------------- fused losses: TV (blocks 0..245) + quant/bal (246..255) + finalize --------
// n_edges (scal[2]) was completed by dupcount_kernel dispatches earlier -> safe to read here.
__global__ __launch_bounds__(1024) void tvquant_kernel(
    const int* __restrict__ src, const int* __restrict__ dst,
    const float* __restrict__ ew, const float* __restrict__ s,
    float* __restrict__ scal, float* __restrict__ out) {
  __shared__ float fsh[16];
  __shared__ int wcnt[2][16];
  int t = threadIdx.x;
  int lane = t & 63, wv = t >> 6;
  if (blockIdx.x < 246) {
    float local = 0.f;
    for (int e = blockIdx.x * 1024 + t; e < N_EDGES; e += 246 * 1024) {
      int a = src[e], b = dst[e];
      float w = ew[e];
      const float* sa = s + (size_t)a * KCL;
      const float* sb = s + (size_t)b * KCL;
      float tv = 0.f;
#pragma unroll
      for (int k = 0; k < KCL; ++k) tv += fabsf(sa[k] - sb[k]);
      local += w * tv;
    }
#pragma unroll
    for (int m = 1; m < 64; m <<= 1) local += __shfl_xor(local, m, 64);
    if (lane == 0) fsh[wv] = local;
    __syncthreads();
    if (t == 0) {
      float tot = 0.f;
#pragma unroll
      for (int i2 = 0; i2 < 16; ++i2) tot += fsh[i2];
      atomicAdd(&scal[0], tot);
    }
  } else {
    int k = blockIdx.x - 246;
    unsigned int v[8];
#pragma unroll
    for (int j = 0; j < 8; ++j)
      v[j] = __float_as_uint(s[(size_t)(t + j * 1024) * KCL + k]);
    unsigned int lo = 0u, hi = 0x3F800000u;  // softmax in (0, 1]
    int p = 0;
    while (lo < hi) {
      unsigned int mid = (lo + hi) >> 1;
      int c = 0;
#pragma unroll
      for (int j = 0; j < 8; ++j) c += (v[j] <= mid) ? 1 : 0;
#pragma unroll
      for (int m = 1; m < 64; m <<= 1) c += __shfl_xor(c, m, 64);
      if (lane == 0) wcnt[p][wv] = c;
      __syncthreads();
      int tot = 0;
#pragma unroll
      for (int i2 = 0; i2 < 16; ++i2) tot += wcnt[p][i2];
      if (tot >= RANK1) hi = mid; else lo = mid + 1;
      p ^= 1;
    }
    float q = __uint_as_float(lo);
    float local = 0.f;
#pragma unroll
    for (int j = 0; j < 8; ++j) {
      float tt = __uint_as_float(v[j]) - q;
      local += (tt >= 0.f) ? 9.f * tt : -tt;
    }
#pragma unroll
    for (int m = 1; m < 64; m <<= 1) local += __shfl_xor(local, m, 64);
    if (lane == 0) fsh[wv] = local;
    __syncthreads();
    if (t == 0) {
      float tot = 0.f;
#pragma unroll
      for (int i2 = 0; i2 < 16; ++i2) tot += fsh[i2];
      atomicAdd(&scal[1], tot);
    }
  }
  // last-done block finalizes (256-block done counter: proven pattern)
  if (t == 0) {
    __threadfence();
    int dn = atomicAdd((int*)(scal + 3), 1);
    if (dn == 255) {
      float tv = atomicAdd(&scal[0], 0.f);
      float asym = atomicAdd(&scal[1], 0.f);
      int ne = atomicAdd((int*)(scal + 2), 0);
      out[N_NODES * KCL] = TV_COEFF_C * (tv / (2.f * (float)ne));
      out[N_NODES * KCL + 1] = BAL_COEFF_C * ((73728.f - asym) / 73728.f);
    }
  }
}

// ---------------- workspace layout (bytes) ----------------
// [0, 33024) is zeroed by ONE memset per launch: cnt + scal (bitmap deleted)
#define OFF_CNT    ((size_t)0)            // 32 KB histogram
#define OFF_SCAL   ((size_t)32768)        // 256 B scalars
#define OFF_OFFS   ((size_t)33024)        // 32 KB + 4
#define OFF_CURSOR ((size_t)65796)        // 32 KB
#define OFF_NORD   ((size_t)98564)        // 32 KB degree-sorted node order
#define OFF_HB     ((size_t)16777216)     // 8 MB bf16 h
#define OFF_OUTB   ((size_t)25165824)     // 8 MB bf16 elu output
#define OFF_ESW    ((size_t)33554432)     // 2 MB int2 (src, weight) sorted by dst
#define OFF_XB     ((size_t)41943040)     // 2 MB bf16 x
#define OFF_W1BT   ((size_t)44040192)
#define OFF_W2BT   ((size_t)44171264)
#define OFF_WM1BT  ((size_t)44695552)
#define OFF_S      ((size_t)44957696)     // softmax s

extern "C" void kernel_launch(void* const* d_in, const int* in_sizes, int n_in,
                              void* d_out, int out_size, void* d_ws, size_t ws_size,
                              hipStream_t stream) {
  const float* x   = (const float*)d_in[0];
  const int*   ei  = (const int*)d_in[1];
  const float* ew  = (const float*)d_in[2];
  const float* W1  = (const float*)d_in[3];
  const float* b1  = (const float*)d_in[4];
  const float* W2  = (const float*)d_in[5];
  const float* b2  = (const float*)d_in[6];
  const float* Wm1 = (const float*)d_in[7];
  const float* bm1 = (const float*)d_in[8];
  const float* Wm2 = (const float*)d_in[9];
  const float* bm2 = (const float*)d_in[10];
  float* out = (float*)d_out;

  char* ws = (char*)d_ws;
  int*            cnt    = (int*)(ws + OFF_CNT);
  float*          scal   = (float*)(ws + OFF_SCAL);
  int*            offs   = (int*)(ws + OFF_OFFS);
  int*            cursor = (int*)(ws + OFF_CURSOR);
  int*            nord   = (int*)(ws + OFF_NORD);
  unsigned short* hb     = (unsigned short*)(ws + OFF_HB);
  unsigned short* outb   = (unsigned short*)(ws + OFF_OUTB);
  int2*           esw    = (int2*)(ws + OFF_ESW);
  unsigned short* xb     = (unsigned short*)(ws + OFF_XB);
  unsigned short* W1bt   = (unsigned short*)(ws + OFF_W1BT);
  unsigned short* W2bt   = (unsigned short*)(ws + OFF_W2BT);
  unsigned short* Wm1bt  = (unsigned short*)(ws + OFF_WM1BT);
  float*          s      = (float*)(ws + OFF_S);

  const int* srcA = ei;
  const int* dstA = ei + N_EDGES;

  hipMemsetAsync(ws, 0, 33024, stream);

  prep_kernel<<<6912, 256, 0, stream>>>(x, W1, W2, Wm1, xb, W1bt, W2bt, Wm1bt, dstA, cnt);
  // layer-1 gemm and the scan are independent (both depend only on prep) -> one dispatch
  gemm1_scan<<<257, 256, 0, stream>>>(xb, W1bt, hb, cnt, offs, cursor, nord);
  fill_kernel<<<1024, 256, 0, stream>>>(srcA, dstA, ew, cursor, esw);
  dupcount_kernel<<<256, 1024, 0, stream>>>(esw, offs, scal);

  // layer 1 gtv (hb from gemm1_scan, esw from fill)
  gtv_node<<<N_NODES / 2, 256, 0, stream>>>(hb, b1, esw, offs, nord, outb);
  // layer 2
  gemm_bt<<<dim3(MP_CH / 128, N_NODES / 128), 256, 0, stream>>>(outb, W2bt, hb, MP_CH, MP_CH);
  gtv_node<<<N_NODES / 2, 256, 0, stream>>>(hb, b2, esw, offs, nord, outb);
  // fused MLP head
  head_fused<<<N_NODES / 32, 256, 0, stream>>>(outb, Wm1bt, bm1, Wm2, bm2, out, s);

  // losses: tv + quant + finalize (n_edges already in scal[2] from dupcount)
  tvquant_kernel<<<256, 1024, 0, stream>>>(srcA, dstA, ew, s, scal, out);
}

// Round 11
// 246.867 us; speedup vs baseline: 1.0408x; 1.0408x over previous
//
#include <hip/hip_runtime.h>

#define N_NODES 8192
#define N_EDGES 262144
#define IN_CH 128
#define MP_CH 512
#define HID 256
#define KCL 10
#define EPS_C 0.001f
#define DELTA_C 0.311f
#define TV_COEFF_C 0.785f
#define BAL_COEFF_C 0.514f
#define RANK1 7373  // N - (N/K+1) + 1 : want smallest v with count(<=v) >= RANK1
#define DBINS 80    // degree histogram bins for load-balance sort

// LESSON (R1-R3, quantified R9): same-line device atomics serialize (~50ns/op, 8 XCD L2s);
// 2048 same-line atomics = 100us. Budget <= ~256 per launch.
// LESSON (R6-R8): gtv_node (~32us/pass) is at its scattered-gather ceiling: DPP reduce
// neutral, depth-2 prefetch neutral, chunk-outer L2 blocking 3x WORSE (serial per-edge).
// LESSON (R5/R10): n_edges restructures (popc-inline, dedup-count) are neutral-to-negative;
// bitmap atomicOr in tvquant + separate popcfin is the measured optimum.
// R11 = exact revert to R9 (249.0us, session best).

typedef __bf16 bf16x8 __attribute__((ext_vector_type(8)));
typedef float f32x4 __attribute__((ext_vector_type(4)));
typedef unsigned short ushort8 __attribute__((ext_vector_type(8)));

__device__ __forceinline__ float bf2f(unsigned short h) {
  union { unsigned int u; float f; } c; c.u = ((unsigned int)h) << 16; return c.f;
}
__device__ __forceinline__ unsigned short f2bf(float f) {
  union { float f; unsigned int u; } c; c.f = f;
  unsigned int r = c.u + 0x7fffu + ((c.u >> 16) & 1u);
  return (unsigned short)(r >> 16);
}

// ---------------- fused prep: bf16 converts + weight transposes + dst histogram -------------
__global__ void prep_kernel(const float* __restrict__ x, const float* __restrict__ W1,
                            const float* __restrict__ W2, const float* __restrict__ Wm1,
                            unsigned short* __restrict__ xb, unsigned short* __restrict__ W1bt,
                            unsigned short* __restrict__ W2bt, unsigned short* __restrict__ Wm1bt,
                            const int* __restrict__ dst, int* __restrict__ cnt) {
  int i = blockIdx.x * 256 + threadIdx.x;
  if (i < 1048576) { xb[i] = f2bf(x[i]); return; }
  i -= 1048576;
  if (i < 65536) { int n = i >> 7, k = i & 127; W1bt[i] = f2bf(W1[k * MP_CH + n]); return; }
  i -= 65536;
  if (i < 262144) { int n = i >> 9, k = i & 511; W2bt[i] = f2bf(W2[k * MP_CH + n]); return; }
  i -= 262144;
  if (i < 131072) { int n = i >> 9, k = i & 511; Wm1bt[i] = f2bf(Wm1[k * HID + n]); return; }
  i -= 131072;
  if (i < N_EDGES) atomicAdd(&cnt[dst[i]], 1);
}

// ---------------- merged: layer-1 GEMM (blocks 0..255) + 256-thread scan (block 256) --------
__global__ __launch_bounds__(256) void gemm1_scan(
    const unsigned short* __restrict__ A, const unsigned short* __restrict__ BT,
    unsigned short* __restrict__ Cb, const int* __restrict__ cnt, int* __restrict__ offs,
    int* __restrict__ cursor, int* __restrict__ nodeorder) {
  if (blockIdx.x < 256) {
    // ---- layer-1 GEMM tile: N=512, K=128; tn = (bid&3)*128, tm = (bid>>2)*128 ----
    __shared__ unsigned short lsm[2 * 128 * 32];
    unsigned short* lA = lsm;
    unsigned short* lB = lsm + 128 * 32;
    const int N = MP_CH, K = IN_CH;
    int lane = threadIdx.x & 63;
    int wv = threadIdx.x >> 6;
    int tm = (blockIdx.x >> 2) * 128, tn = (blockIdx.x & 3) * 128;
    int wm = (wv >> 1) * 64, wn = (wv & 1) * 64;
    int rA = lane & 15, quad = lane >> 4;
    f32x4 acc[4][4];
#pragma unroll
    for (int i = 0; i < 4; ++i)
#pragma unroll
      for (int j = 0; j < 4; ++j) acc[i][j] = (f32x4){0.f, 0.f, 0.f, 0.f};
    int arow = wv * 32 + (lane >> 2);
    int acol = (lane & 3) * 8;
    for (int k0 = 0; k0 < K; k0 += 32) {
#pragma unroll
      for (int c = 0; c < 2; ++c) {
        const unsigned short* ga = A + (size_t)(tm + arow + c * 16) * K + k0 + acol;
        __builtin_amdgcn_global_load_lds(
            (const __attribute__((address_space(1))) unsigned int*)ga,
            (__attribute__((address_space(3))) unsigned int*)(lA + (wv * 32 + c * 16) * 32),
            16, 0, 0);
        const unsigned short* gb = BT + (size_t)(tn + arow + c * 16) * K + k0 + acol;
        __builtin_amdgcn_global_load_lds(
            (const __attribute__((address_space(1))) unsigned int*)gb,
            (__attribute__((address_space(3))) unsigned int*)(lB + (wv * 32 + c * 16) * 32),
            16, 0, 0);
      }
      __syncthreads();
      bf16x8 af[4], bfr[4];
#pragma unroll
      for (int i = 0; i < 4; ++i)
        af[i] = *(const bf16x8*)(lA + (wm + i * 16 + rA) * 32 + quad * 8);
#pragma unroll
      for (int j = 0; j < 4; ++j)
        bfr[j] = *(const bf16x8*)(lB + (wn + j * 16 + rA) * 32 + quad * 8);
#pragma unroll
      for (int i = 0; i < 4; ++i)
#pragma unroll
        for (int j = 0; j < 4; ++j)
          acc[i][j] = __builtin_amdgcn_mfma_f32_16x16x32_bf16(af[i], bfr[j], acc[i][j], 0, 0, 0);
      __syncthreads();
    }
    float* fbuf = (float*)lsm;
    int band = threadIdx.x >> 7;
    int rrow = (threadIdx.x >> 3) & 15;
    int cg = threadIdx.x & 7;
#pragma unroll
    for (int i = 0; i < 4; ++i) {
#pragma unroll
      for (int j = 0; j < 4; ++j)
#pragma unroll
        for (int r = 0; r < 4; ++r)
          fbuf[(wv >> 1) * (16 * 128) + (quad * 4 + r) * 128 + (wn + j * 16 + rA)] =
              acc[i][j][r];
      __syncthreads();
      const float* sr = fbuf + band * (16 * 128) + rrow * 128 + cg * 16;
      unsigned short ov[16];
#pragma unroll
      for (int c = 0; c < 16; ++c) ov[c] = f2bf(sr[c]);
      size_t gbase = (size_t)(tm + band * 64 + i * 16 + rrow) * N + tn + cg * 16;
      *(ushort8*)(Cb + gbase) = *(ushort8*)ov;
      *(ushort8*)(Cb + gbase + 8) = *(ushort8*)(ov + 8);
      __syncthreads();
    }
  } else {
    // ---- 256-thread scan: prefix-sum + degree-descending counting sort (R1-verified) ----
    __shared__ int ts[256];
    __shared__ int dh[DBINS];
    int t = threadIdx.x;
    int v[32]; int ssum = 0;
#pragma unroll
    for (int j = 0; j < 32; ++j) { v[j] = cnt[t * 32 + j]; ssum += v[j]; }
    if (t < DBINS) dh[t] = 0;
    ts[t] = ssum; __syncthreads();
    for (int off = 1; off < 256; off <<= 1) {
      int add = (t >= off) ? ts[t - off] : 0;
      __syncthreads();
      ts[t] += add;
      __syncthreads();
    }
    int base = ts[t] - ssum;  // exclusive prefix
#pragma unroll
    for (int j = 0; j < 32; ++j) {
      offs[t * 32 + j] = base; cursor[t * 32 + j] = base; base += v[j];
      int key = v[j] < (DBINS - 1) ? v[j] : (DBINS - 1);
      atomicAdd(&dh[(DBINS - 1) - key], 1);  // descending-degree bins
    }
    if (t == 255) offs[N_NODES] = ts[255];
    __syncthreads();
    if (t == 0) {
      int acc0 = 0;
      for (int b = 0; b < DBINS; ++b) { int c = dh[b]; dh[b] = acc0; acc0 += c; }
    }
    __syncthreads();
#pragma unroll
    for (int j = 0; j < 32; ++j) {
      int key = v[j] < (DBINS - 1) ? v[j] : (DBINS - 1);
      int pos = atomicAdd(&dh[(DBINS - 1) - key], 1);
      nodeorder[pos] = t * 32 + j;
    }
  }
}

// pack (src, weight) sorted by dst
__global__ void fill_kernel(const int* __restrict__ src, const int* __restrict__ dst,
                            const float* __restrict__ ew, int* __restrict__ cursor,
                            int2* __restrict__ esw) {
  for (int e = blockIdx.x * blockDim.x + threadIdx.x; e < N_EDGES; e += gridDim.x * blockDim.x) {
    int p = atomicAdd(&cursor[dst[e]], 1);
    esw[p] = make_int2(src[e], __float_as_int(ew[e]));
  }
}

// ---------------- MFMA GEMM: Cb[M,N] bf16 = A[M,K] @ BT[N,K]^T  (layer 2) -------------------
__global__ __launch_bounds__(256) void gemm_bt(
    const unsigned short* __restrict__ A, const unsigned short* __restrict__ BT,
    unsigned short* __restrict__ Cb, int N, int K) {
  __shared__ unsigned short lsm[2 * 128 * 32];  // lA | lB ; reused as f32 buf in epilogue
  unsigned short* lA = lsm;
  unsigned short* lB = lsm + 128 * 32;
  int lane = threadIdx.x & 63;
  int wv = threadIdx.x >> 6;
  int tm = blockIdx.y * 128, tn = blockIdx.x * 128;
  int wm = (wv >> 1) * 64, wn = (wv & 1) * 64;
  int rA = lane & 15, quad = lane >> 4;
  f32x4 acc[4][4];
#pragma unroll
  for (int i = 0; i < 4; ++i)
#pragma unroll
    for (int j = 0; j < 4; ++j) acc[i][j] = (f32x4){0.f, 0.f, 0.f, 0.f};

  int arow = wv * 32 + (lane >> 2);
  int acol = (lane & 3) * 8;

  for (int k0 = 0; k0 < K; k0 += 32) {
#pragma unroll
    for (int c = 0; c < 2; ++c) {
      const unsigned short* ga = A + (size_t)(tm + arow + c * 16) * K + k0 + acol;
      __builtin_amdgcn_global_load_lds(
          (const __attribute__((address_space(1))) unsigned int*)ga,
          (__attribute__((address_space(3))) unsigned int*)(lA + (wv * 32 + c * 16) * 32),
          16, 0, 0);
      const unsigned short* gb = BT + (size_t)(tn + arow + c * 16) * K + k0 + acol;
      __builtin_amdgcn_global_load_lds(
          (const __attribute__((address_space(1))) unsigned int*)gb,
          (__attribute__((address_space(3))) unsigned int*)(lB + (wv * 32 + c * 16) * 32),
          16, 0, 0);
    }
    __syncthreads();
    bf16x8 af[4], bfr[4];
#pragma unroll
    for (int i = 0; i < 4; ++i)
      af[i] = *(const bf16x8*)(lA + (wm + i * 16 + rA) * 32 + quad * 8);
#pragma unroll
    for (int j = 0; j < 4; ++j)
      bfr[j] = *(const bf16x8*)(lB + (wn + j * 16 + rA) * 32 + quad * 8);
#pragma unroll
    for (int i = 0; i < 4; ++i)
#pragma unroll
      for (int j = 0; j < 4; ++j)
        acc[i][j] = __builtin_amdgcn_mfma_f32_16x16x32_bf16(af[i], bfr[j], acc[i][j], 0, 0, 0);
    __syncthreads();
  }

  // LDS re-tile epilogue: coalesced 16B bf16 stores
  float* fbuf = (float*)lsm;
  int band = threadIdx.x >> 7;
  int rrow = (threadIdx.x >> 3) & 15;
  int cg = threadIdx.x & 7;
#pragma unroll
  for (int i = 0; i < 4; ++i) {
#pragma unroll
    for (int j = 0; j < 4; ++j)
#pragma unroll
      for (int r = 0; r < 4; ++r)
        fbuf[(wv >> 1) * (16 * 128) + (quad * 4 + r) * 128 + (wn + j * 16 + rA)] =
            acc[i][j][r];
    __syncthreads();
    const float* sr = fbuf + band * (16 * 128) + rrow * 128 + cg * 16;
    unsigned short ov[16];
#pragma unroll
    for (int c = 0; c < 16; ++c) ov[c] = f2bf(sr[c]);
    size_t gbase = (size_t)(tm + band * 64 + i * 16 + rrow) * N + tn + cg * 16;
    *(ushort8*)(Cb + gbase) = *(ushort8*)ov;
    *(ushort8*)(Cb + gbase + 8) = *(ushort8*)(ov + 8);
    __syncthreads();
  }
}

// ---------------- fused GTV node pass: TWO waves per node (half edge list each) -------------
// R4-proven structure (~32us/pass): parallel 1KB gathers, shfl-butterfly reduce.
__global__ __launch_bounds__(256, 8) void gtv_node(
    const unsigned short* __restrict__ hb, const float* __restrict__ bias,
    const int2* __restrict__ esw, const int* __restrict__ offs,
    const int* __restrict__ nodeorder, unsigned short* __restrict__ outb) {
  __shared__ float sacc[2][MP_CH];
  int lane = threadIdx.x & 63;
  int wv = threadIdx.x >> 6;
  int pair = wv >> 1;          // 0,1 : node slot within block
  int half = wv & 1;           // 0,1 : which half of the edge list
  int d = __builtin_amdgcn_readfirstlane(nodeorder[blockIdx.x * 2 + pair]);
  ushort8 hdv = ((const ushort8*)(hb + (size_t)d * MP_CH))[lane];
  float hd[8], acc[8];
#pragma unroll
  for (int j = 0; j < 8; ++j) { hd[j] = bf2f(hdv[j]); acc[j] = 0.f; }
  int n0 = offs[d], n1 = offs[d + 1];
  int mid = n0 + ((n1 - n0 + 1) >> 1);
  int e0 = half ? mid : n0;
  int e1 = half ? n1 : mid;
  int i = e0;
  for (; i + 1 < e1; i += 2) {
    int2 ma = esw[i], mb = esw[i + 1];
    float wa = __int_as_float(ma.y), wb = __int_as_float(mb.y);
    ushort8 va = ((const ushort8*)(hb + (size_t)ma.x * MP_CH))[lane];
    ushort8 vb = ((const ushort8*)(hb + (size_t)mb.x * MP_CH))[lane];
    float pa = 0.f, pb = 0.f;
#pragma unroll
    for (int j = 0; j < 8; ++j) {
      pa += fabsf(hd[j] - bf2f(va[j]));
      pb += fabsf(hd[j] - bf2f(vb[j]));
    }
#pragma unroll
    for (int m = 1; m < 64; m <<= 1) { pa += __shfl_xor(pa, m, 64); pb += __shfl_xor(pb, m, 64); }
    float ga = wa * __builtin_amdgcn_rcpf(fmaxf(pa, EPS_C));
    float gb = wb * __builtin_amdgcn_rcpf(fmaxf(pb, EPS_C));
#pragma unroll
    for (int j = 0; j < 8; ++j)
      acc[j] += ga * (hd[j] - bf2f(va[j])) + gb * (hd[j] - bf2f(vb[j]));
  }
  if (i < e1) {
    int2 m0 = esw[i];
    float w = __int_as_float(m0.y);
    ushort8 sv = ((const ushort8*)(hb + (size_t)m0.x * MP_CH))[lane];
    float part = 0.f;
#pragma unroll
    for (int j = 0; j < 8; ++j) part += fabsf(hd[j] - bf2f(sv[j]));
#pragma unroll
    for (int m = 1; m < 64; m <<= 1) part += __shfl_xor(part, m, 64);
    float g = w * __builtin_amdgcn_rcpf(fmaxf(part, EPS_C));
#pragma unroll
    for (int j = 0; j < 8; ++j) acc[j] += g * (hd[j] - bf2f(sv[j]));
  }
  // combine halves: half1 publishes, half0 merges + does the epilogue
  if (half) {
#pragma unroll
    for (int j = 0; j < 8; ++j) sacc[pair][lane * 8 + j] = acc[j];
  }
  __syncthreads();
  if (!half) {
    const f32x4* br = (const f32x4*)(bias + lane * 8);
    f32x4 b0 = br[0], b1 = br[1];
    unsigned short ov[8];
#pragma unroll
    for (int j = 0; j < 8; ++j) {
      float tot = acc[j] + sacc[pair][lane * 8 + j];
      float bv = (j < 4) ? b0[j] : b1[j - 4];
      float o = hd[j] - DELTA_C * tot + bv;
      o = (o > 0.f) ? o : (expf(o) - 1.f);
      ov[j] = f2bf(o);
    }
    *((ushort8*)(outb + (size_t)d * MP_CH) + lane) = *(ushort8*)ov;
  }
}

// ---------------- fused MLP head: relu(outb@Wm1+b) in MFMA, then @Wm2+b2, softmax -----------
__global__ __launch_bounds__(256) void head_fused(
    const unsigned short* __restrict__ A,   // outb [8192][512] bf16
    const unsigned short* __restrict__ BT,  // Wm1bt [256][512] bf16
    const float* __restrict__ bm1v, const float* __restrict__ Wm2v,
    const float* __restrict__ bm2v, float* __restrict__ out, float* __restrict__ s) {
  __shared__ unsigned short lA[32 * 32];    // 2 KB
  __shared__ unsigned short lB[256 * 32];   // 16 KB
  __shared__ float hbuf[256 * 41];          // 42 KB, col-major padded
  __shared__ float lW2[HID * KCL];          // 10 KB
  __shared__ float lb1[HID];
  __shared__ float lb2[KCL];
  int t = threadIdx.x;
  int lane = t & 63, wv = t >> 6;
  int rA = lane & 15, quad = lane >> 4;
  int m0 = blockIdx.x * 32;

  for (int i2 = t; i2 < HID * KCL; i2 += 256) lW2[i2] = Wm2v[i2];
  lb1[t < HID ? t : 0] = bm1v[t < HID ? t : 0];
  if (t < KCL) lb2[t] = bm2v[t];

  f32x4 acc[2][4];
#pragma unroll
  for (int i = 0; i < 2; ++i)
#pragma unroll
    for (int j = 0; j < 4; ++j) acc[i][j] = (f32x4){0.f, 0.f, 0.f, 0.f};

  for (int k0 = 0; k0 < MP_CH; k0 += 32) {
    if (wv < 2) {
      int row = wv * 16 + (lane >> 2);
      const unsigned short* ga = A + (size_t)(m0 + row) * MP_CH + k0 + (lane & 3) * 8;
      __builtin_amdgcn_global_load_lds(
          (const __attribute__((address_space(1))) unsigned int*)ga,
          (__attribute__((address_space(3))) unsigned int*)(lA + (wv * 16) * 32), 16, 0, 0);
    }
#pragma unroll
    for (int q = 0; q < 4; ++q) {
      int idx = wv * 4 + q;
      int row = idx * 16 + (lane >> 2);
      const unsigned short* gb = BT + (size_t)row * MP_CH + k0 + (lane & 3) * 8;
      __builtin_amdgcn_global_load_lds(
          (const __attribute__((address_space(1))) unsigned int*)gb,
          (__attribute__((address_space(3))) unsigned int*)(lB + (idx * 16) * 32), 16, 0, 0);
    }
    __syncthreads();
    bf16x8 af[2], bfr[4];
#pragma unroll
    for (int i = 0; i < 2; ++i)
      af[i] = *(const bf16x8*)(lA + (i * 16 + rA) * 32 + quad * 8);
#pragma unroll
    for (int j = 0; j < 4; ++j)
      bfr[j] = *(const bf16x8*)(lB + (wv * 64 + j * 16 + rA) * 32 + quad * 8);
#pragma unroll
    for (int i = 0; i < 2; ++i)
#pragma unroll
      for (int j = 0; j < 4; ++j)
        acc[i][j] = __builtin_amdgcn_mfma_f32_16x16x32_bf16(af[i], bfr[j], acc[i][j], 0, 0, 0);
    __syncthreads();
  }

  // epilogue 1: h = relu(acc + bm1) -> LDS col-major [col][row], stride 41
#pragma unroll
  for (int i = 0; i < 2; ++i)
#pragma unroll
    for (int j = 0; j < 4; ++j)
#pragma unroll
      for (int r = 0; r < 4; ++r) {
        int row = i * 16 + quad * 4 + r;
        int col = wv * 64 + j * 16 + rA;
        hbuf[col * 41 + row] = fmaxf(acc[i][j][r] + lb1[col], 0.f);
      }
  __syncthreads();

  // epilogue 2: s_logits[row] = h[row] @ Wm2 + bm2 ; softmax -> s
  int row = t >> 3, g = t & 7;
  float p[KCL];
#pragma unroll
  for (int n = 0; n < KCL; ++n) p[n] = 0.f;
#pragma unroll
  for (int k = 0; k < 32; ++k) {
    int col = k * 8 + g;
    float hv = hbuf[col * 41 + row];
    const float* wr = lW2 + col * KCL;
#pragma unroll
    for (int n = 0; n < KCL; ++n) p[n] += hv * wr[n];
  }
#pragma unroll
  for (int n = 0; n < KCL; ++n) {
    p[n] += __shfl_xor(p[n], 1, 64);
    p[n] += __shfl_xor(p[n], 2, 64);
    p[n] += __shfl_xor(p[n], 4, 64);
  }
  if (g == 0) {
    float vv[KCL]; float mx = -1e30f;
    size_t gr = (size_t)(m0 + row);
#pragma unroll
    for (int n = 0; n < KCL; ++n) {
      vv[n] = p[n] + lb2[n];
      out[gr * KCL + n] = vv[n];
      mx = fmaxf(mx, vv[n]);
    }
    float sum = 0.f;
#pragma unroll
    for (int n = 0; n < KCL; ++n) { vv[n] = expf(vv[n] - mx); sum += vv[n]; }
    float inv = 1.f / sum;
#pragma unroll
    for (int n = 0; n < KCL; ++n) s[gr * KCL + n] = vv[n] * inv;
  }
}

// ---------------- fused losses A: TV (blocks 0..245) + quant/bal (blocks 246..255) ----------
__global__ __launch_bounds__(1024) void tvquant_kernel(
    const int* __restrict__ src, const int* __restrict__ dst,
    const float* __restrict__ ew, const float* __restrict__ s,
    unsigned int* __restrict__ bitmap, float* __restrict__ scal) {
  __shared__ float fsh[16];
  __shared__ int wcnt[2][16];
  int t = threadIdx.x;
  int lane = t & 63, wv = t >> 6;
  if (blockIdx.x < 246) {
    float local = 0.f;
    for (int e = blockIdx.x * 1024 + t; e < N_EDGES; e += 246 * 1024) {
      int a = src[e], b = dst[e];
      float w = ew[e];
      const float* sa = s + (size_t)a * KCL;
      const float* sb = s + (size_t)b * KCL;
      float tv = 0.f;
#pragma unroll
      for (int k = 0; k < KCL; ++k) tv += fabsf(sa[k] - sb[k]);
      local += w * tv;
      if (w != 0.f) {
        unsigned int key = ((unsigned int)a << 13) | (unsigned int)b;
        atomicOr(&bitmap[key >> 5], 1u << (key & 31u));
      }
    }
#pragma unroll
    for (int m = 1; m < 64; m <<= 1) local += __shfl_xor(local, m, 64);
    if (lane == 0) fsh[wv] = local;
    __syncthreads();
    if (t == 0) {
      float tot = 0.f;
#pragma unroll
      for (int i2 = 0; i2 < 16; ++i2) tot += fsh[i2];
      atomicAdd(&scal[0], tot);
    }
  } else {
    int k = blockIdx.x - 246;
    unsigned int v[8];
#pragma unroll
    for (int j = 0; j < 8; ++j)
      v[j] = __float_as_uint(s[(size_t)(t + j * 1024) * KCL + k]);
    unsigned int lo = 0u, hi = 0x3F800000u;  // softmax in (0, 1]
    int p = 0;
    while (lo < hi) {
      unsigned int mid = (lo + hi) >> 1;
      int c = 0;
#pragma unroll
      for (int j = 0; j < 8; ++j) c += (v[j] <= mid) ? 1 : 0;
#pragma unroll
      for (int m = 1; m < 64; m <<= 1) c += __shfl_xor(c, m, 64);
      if (lane == 0) wcnt[p][wv] = c;
      __syncthreads();
      int tot = 0;
#pragma unroll
      for (int i2 = 0; i2 < 16; ++i2) tot += wcnt[p][i2];
      if (tot >= RANK1) hi = mid; else lo = mid + 1;
      p ^= 1;
    }
    float q = __uint_as_float(lo);
    float local = 0.f;
#pragma unroll
    for (int j = 0; j < 8; ++j) {
      float tt = __uint_as_float(v[j]) - q;
      local += (tt >= 0.f) ? 9.f * tt : -tt;
    }
#pragma unroll
    for (int m = 1; m < 64; m <<= 1) local += __shfl_xor(local, m, 64);
    if (lane == 0) fsh[wv] = local;
    __syncthreads();
    if (t == 0) {
      float tot = 0.f;
#pragma unroll
      for (int i2 = 0; i2 < 16; ++i2) tot += fsh[i2];
      atomicAdd(&scal[1], tot);
    }
  }
}

// ---------------- fused losses B: popcount n_edges + last-block finalize ---------------------
__global__ __launch_bounds__(1024) void popcfin_kernel(const unsigned int* __restrict__ bm,
                                                       float* __restrict__ scal,
                                                       float* __restrict__ out) {
  __shared__ int ish[16];
  int t = threadIdx.x;
  int lane = t & 63, wv = t >> 6;
  int local = 0;
  for (int i = blockIdx.x * 1024 + t; i < (1 << 21); i += 256 * 1024)
    local += __popc(bm[i]);
#pragma unroll
  for (int m = 1; m < 64; m <<= 1) local += __shfl_xor(local, m, 64);
  if (lane == 0) ish[wv] = local;
  __syncthreads();
  if (t == 0) {
    int tot = 0;
#pragma unroll
    for (int i2 = 0; i2 < 16; ++i2) tot += ish[i2];
    atomicAdd((int*)(scal + 2), tot);
    __threadfence();
    int d = atomicAdd((int*)(scal + 3), 1);
    if (d == 255) {
      float tv = scal[0], asym = scal[1];
      float nedges = (float)(*(int*)(scal + 2));
      out[N_NODES * KCL] = TV_COEFF_C * (tv / (2.f * nedges));
      out[N_NODES * KCL + 1] = BAL_COEFF_C * ((73728.f - asym) / 73728.f);
    }
  }
}

// ---------------- workspace layout (bytes) ----------------
// [0, 8421632) is zeroed by ONE memset per launch: bitmap + cnt + scal
#define OFF_BM     ((size_t)0)            // 8 MB n_edges bitmap
#define OFF_CNT    ((size_t)8388608)      // 32 KB histogram
#define OFF_SCAL   ((size_t)8421376)      // 256 B scalars
#define OFF_OFFS   ((size_t)8421888)      // 32 KB + 4
#define OFF_CURSOR ((size_t)8454912)      // 32 KB
#define OFF_NORD   ((size_t)8487936)      // 32 KB degree-sorted node order
#define OFF_HB     ((size_t)16777216)     // 8 MB bf16 h
#define OFF_OUTB   ((size_t)25165824)     // 8 MB bf16 elu output
#define OFF_ESW    ((size_t)33554432)     // 2 MB int2 (src, weight) sorted by dst
#define OFF_XB     ((size_t)41943040)     // 2 MB bf16 x
#define OFF_W1BT   ((size_t)44040192)
#define OFF_W2BT   ((size_t)44171264)
#define OFF_WM1BT  ((size_t)44695552)
#define OFF_S      ((size_t)44957696)     // softmax s

extern "C" void kernel_launch(void* const* d_in, const int* in_sizes, int n_in,
                              void* d_out, int out_size, void* d_ws, size_t ws_size,
                              hipStream_t stream) {
  const float* x   = (const float*)d_in[0];
  const int*   ei  = (const int*)d_in[1];
  const float* ew  = (const float*)d_in[2];
  const float* W1  = (const float*)d_in[3];
  const float* b1  = (const float*)d_in[4];
  const float* W2  = (const float*)d_in[5];
  const float* b2  = (const float*)d_in[6];
  const float* Wm1 = (const float*)d_in[7];
  const float* bm1 = (const float*)d_in[8];
  const float* Wm2 = (const float*)d_in[9];
  const float* bm2 = (const float*)d_in[10];
  float* out = (float*)d_out;

  char* ws = (char*)d_ws;
  unsigned int*   bitmap = (unsigned int*)(ws + OFF_BM);
  int*            cnt    = (int*)(ws + OFF_CNT);
  float*          scal   = (float*)(ws + OFF_SCAL);
  int*            offs   = (int*)(ws + OFF_OFFS);
  int*            cursor = (int*)(ws + OFF_CURSOR);
  int*            nord   = (int*)(ws + OFF_NORD);
  unsigned short* hb     = (unsigned short*)(ws + OFF_HB);
  unsigned short* outb   = (unsigned short*)(ws + OFF_OUTB);
  int2*           esw    = (int2*)(ws + OFF_ESW);
  unsigned short* xb     = (unsigned short*)(ws + OFF_XB);
  unsigned short* W1bt   = (unsigned short*)(ws + OFF_W1BT);
  unsigned short* W2bt   = (unsigned short*)(ws + OFF_W2BT);
  unsigned short* Wm1bt  = (unsigned short*)(ws + OFF_WM1BT);
  float*          s      = (float*)(ws + OFF_S);

  const int* srcA = ei;
  const int* dstA = ei + N_EDGES;

  // one memset covers bitmap + cnt + scal (contiguous)
  hipMemsetAsync(ws, 0, 8421632, stream);

  prep_kernel<<<6912, 256, 0, stream>>>(x, W1, W2, Wm1, xb, W1bt, W2bt, Wm1bt, dstA, cnt);
  // layer-1 gemm and the scan are independent (both depend only on prep) -> one dispatch
  gemm1_scan<<<257, 256, 0, stream>>>(xb, W1bt, hb, cnt, offs, cursor, nord);
  fill_kernel<<<1024, 256, 0, stream>>>(srcA, dstA, ew, cursor, esw);

  // layer 1 gtv (hb from gemm1_scan, esw from fill)
  gtv_node<<<N_NODES / 2, 256, 0, stream>>>(hb, b1, esw, offs, nord, outb);
  // layer 2
  gemm_bt<<<dim3(MP_CH / 128, N_NODES / 128), 256, 0, stream>>>(outb, W2bt, hb, MP_CH, MP_CH);
  gtv_node<<<N_NODES / 2, 256, 0, stream>>>(hb, b2, esw, offs, nord, outb);
  // fused MLP head
  head_fused<<<N_NODES / 32, 256, 0, stream>>>(outb, Wm1bt, bm1, Wm2, bm2, out, s);

  // losses: tv + quant (bitmap set), then popc + finalize
  tvquant_kernel<<<256, 1024, 0, stream>>>(srcA, dstA, ew, s, bitmap, scal);
  popcfin_kernel<<<256, 1024, 0, stream>>>(bitmap, scal, out);
}